// Round 10
// baseline (354.503 us; speedup 1.0000x reference)
//
#include <hip/hip_runtime.h>

// Masked attention B=8, NQ=1024, S=2048, D=512, fp32 in/out.
// prep: K -> Kf fp16; V -> Vt fp16 [b][d][s]; mask -> bit-packed Mp (2MB);
//       zero the 64 split-k counters (stream-ordered before attn).
// attn_flash r18 = r12 compute core VERBATIM (83.5-84.7us over 3 runs; four
//   structural redesigns r13/r14/r16/r17 all landed 84-134 -> this is the
//   2-waves/SIMD floor forced by D=512's 128-reg O-state per wave) + FUSED
//   split-k combine:
//   - after Opart/M/L stores: __threadfence (device-scope release),
//     one atomicAdd per WG on Cnt[b*8+qt]; the LAST of the SPLIT arrivals
//     (no waiting) merges the S-parts for its 128q x 512d and writes O.
//   - removes the combine kernel launch + graph node; combine traffic
//     (~770KB/combining-WG, L2-resident Opart) overlaps other WGs' attn.
//   - +2.5KB LDS (sW/sInv) -> 145KB, still 1 WG/CU.

#define Bz 8
#define NQz 1024
#define Sz 2048
#define Dz 512
#define QTT 128   // q rows per WG (8 waves x 16)
#define TS 32
#define KP 520    // sK row pitch (f16); 1040B rows
#define PP 40     // sP row pitch (f16)

typedef _Float16 f16x8 __attribute__((ext_vector_type(8)));
typedef float f32x4 __attribute__((ext_vector_type(4)));
typedef unsigned short ushort_t;

#define AS1(p) ((const __attribute__((address_space(1))) unsigned int*)(p))
#define AS3(p) ((__attribute__((address_space(3))) unsigned int*)(p))
#define DRAIN_ALL() __builtin_amdgcn_s_waitcnt(0)

__device__ __forceinline__ ushort_t f2h(float x) {
  _Float16 h = (_Float16)x;  // RNE
  return __builtin_bit_cast(ushort_t, h);
}
__device__ __forceinline__ float h2f(ushort_t u) {
  return (float)__builtin_bit_cast(_Float16, u);
}

// ---- prep: K -> fp16 | V -> Vt fp16 transposed | mask -> bitpack ----
__global__ __launch_bounds__(256)
void prep(const float* __restrict__ K, const float* __restrict__ V,
          const int* __restrict__ Mi, ushort_t* __restrict__ Kf,
          ushort_t* __restrict__ Vt, unsigned* __restrict__ Mp,
          int* __restrict__ Cnt) {
  __shared__ ushort_t sT[64][41];
  const int t = threadIdx.x;
  int bx = blockIdx.x;
  if (bx < 2048) {  // K fp32 -> fp16: 16 elems/thread, 4 independent streams
    if (bx == 0 && t < 64) Cnt[t] = 0;   // zero split-k counters each run
    const size_t base = (size_t)bx * 4096 + t * 4;
#pragma unroll
    for (int i = 0; i < 4; ++i) {
      size_t e = base + i * 1024;
      float4 v = *(const float4*)(K + e);
      uint2 w;
      w.x = (unsigned)f2h(v.x) | ((unsigned)f2h(v.y) << 16);
      w.y = (unsigned)f2h(v.z) | ((unsigned)f2h(v.w) << 16);
      *(uint2*)(Kf + e) = w;
    }
    return;
  }
  bx -= 2048;
  if (bx < 4096) {  // V transpose, 64s x 32d tiles, 128B write segments
    const int b = bx >> 9;
    const int rest = bx & 511;
    const int st = rest >> 4;
    const int dt = rest & 15;
    const int s0 = st * 64, d0 = dt * 32;
    const float* Vb = V + ((size_t)b * Sz + s0) * Dz + d0;
#pragma unroll
    for (int i = 0; i < 2; ++i) {
      int idx = t + 256 * i;
      int s = idx >> 3;
      int dc = (idx & 7) * 4;
      float4 v = *(const float4*)(Vb + (size_t)s * Dz + dc);
      uint2 w;
      w.x = (unsigned)f2h(v.x) | ((unsigned)f2h(v.y) << 16);
      w.y = (unsigned)f2h(v.z) | ((unsigned)f2h(v.w) << 16);
      *(uint2*)(&sT[s][dc]) = w;
    }
    __syncthreads();
    ushort_t* VtB = Vt + ((size_t)b * Dz + d0) * Sz + s0;
    int d = t >> 3, c = t & 7;
    uint4 u;
    ushort_t* tp = (ushort_t*)&u;
#pragma unroll
    for (int j = 0; j < 8; ++j) tp[j] = sT[c * 8 + j][d];
    *(uint4*)(VtB + (size_t)d * Sz + c * 8) = u;
    return;
  }
  bx -= 4096;  // mask bitpack: 4096 ints/block over 4 iterations
  const int lane = t & 63;
#pragma unroll
  for (int i = 0; i < 4; ++i) {
    const size_t base = (size_t)bx * 4096 + i * 1024 + t * 4;
    const int4 mv = *(const int4*)(Mi + base);
    unsigned nib = (mv.x ? 1u : 0u) | (mv.y ? 2u : 0u) |
                   (mv.z ? 4u : 0u) | (mv.w ? 8u : 0u);
    unsigned v = nib << ((lane & 7) * 4);
    v |= __shfl_xor(v, 1);
    v |= __shfl_xor(v, 2);
    v |= __shfl_xor(v, 4);
    if ((lane & 7) == 0) Mp[bx * 128 + i * 32 + (t >> 3)] = v;
  }
}

// ---------------- attention + fused split-k combine ----------------
template <int SPLIT>
__global__ __launch_bounds__(512, 2)
void attn_flash(const float* __restrict__ Q, const unsigned* __restrict__ Mp,
                const ushort_t* __restrict__ Kf, const ushort_t* __restrict__ Vt,
                ushort_t* __restrict__ Opart, float* __restrict__ Mpart,
                float* __restrict__ Lpart, int* __restrict__ Cnt,
                float* __restrict__ Out) {
  __shared__ ushort_t sK[2][TS][KP];    // 66.56 KB
  __shared__ ushort_t sV[2][Dz][TS];    // 65.54 KB (16B-slot XOR-swizzled)
  __shared__ ushort_t sP[8][16][PP];    // 10.24 KB, per-wave private strips

  const int tid  = threadIdx.x;
  const int wave = tid >> 6;
  const int lane = tid & 63;
  const int l16  = lane & 15;
  const int quad = lane >> 4;

  const int bxr = blockIdx.x;
  const int b   = bxr & 7;               // XCD swizzle: b == XCD
  const int rest = bxr >> 3;
  const int qt  = rest / SPLIT;
  const int sh  = rest % SPLIT;
  const int q0  = qt * QTT;
  const int SLEN = Sz / SPLIT;
  const int NTt  = SLEN / TS;
  const int sbeg = sh * SLEN;
  const int qw   = q0 + wave * 16;       // this wave's q base

  const float*    Qb  = Q  + ((size_t)b * NQz + qw) * Dz;
  const ushort_t* KfB = Kf + (size_t)b * Sz * Dz;
  const ushort_t* VtB = Vt + (size_t)b * Dz * Sz;
  const unsigned* MpB = Mp + ((size_t)b * NQz + qw) * (Sz / 32);

  // sV swizzle: physical 16B slot = logical_quad ^ ((d>>1)&3).
  const int vql  = (lane & 3) ^ ((lane >> 3) & 3);   // DMA source slot
  const int vcol = (quad ^ ((l16 >> 1) & 3)) * 8;    // read slot (f16 elems)

  auto issue_tile = [&](int s0n, int bsel) {
#pragma unroll
    for (int j = 0; j < 4; ++j) {  // K: 32 rows, 1 row (1024B) per instr
      int row = wave * 4 + j;
      const ushort_t* gp = KfB + (size_t)(s0n + row) * Dz + lane * 8;
      __builtin_amdgcn_global_load_lds(AS1(gp), AS3(&sK[bsel][row][0]), 16, 0, 0);
    }
#pragma unroll
    for (int j = 0; j < 4; ++j) {  // V: 512 d-rows of 64B, 16 rows per instr
      int dbase = wave * 64 + j * 16;
      int d = dbase + (lane >> 2);
      const ushort_t* gp = VtB + (size_t)d * Sz + s0n + vql * 8;
      __builtin_amdgcn_global_load_lds(AS1(gp), AS3(&sV[bsel][dbase][0]), 16, 0, 0);
    }
  };
  auto load_mask = [&](int s0n) -> unsigned {
    return MpB[(size_t)l16 * (Sz / 32) + (s0n >> 5)];
  };

  // ---- prologue: DMA(0), mask(0), Q frags, DMA(1) ----
  issue_tile(sbeg, 0);
  unsigned msk_cur = load_mask(sbeg);

  f16x8 qa[16];  // Q rows qw+l16, fp16; B-operand of swapped QK
  {
    const float* qrow = Qb + (size_t)l16 * Dz;
#pragma unroll
    for (int kk = 0; kk < 16; ++kk) {
      const float4 a = *(const float4*)(qrow + kk * 32 + quad * 8);
      const float4 c = *(const float4*)(qrow + kk * 32 + quad * 8 + 4);
      f16x8 h;
      h[0] = (_Float16)a.x; h[1] = (_Float16)a.y;
      h[2] = (_Float16)a.z; h[3] = (_Float16)a.w;
      h[4] = (_Float16)c.x; h[5] = (_Float16)c.y;
      h[6] = (_Float16)c.z; h[7] = (_Float16)c.w;
      qa[kk] = h;
    }
  }
  if (NTt > 1) issue_tile(sbeg + TS, 1);
  DRAIN_ALL();       // each wave retires its own DMA portion...
  __syncthreads();   // ...then barrier => whole tile 0 (and 1) visible

  float m_ln = -1e30f, l_ln = 0.0f;  // running stats for q = qw + l16
  f32x4 oacc[32];
#pragma unroll
  for (int nt = 0; nt < 32; ++nt) oacc[nt] = (f32x4){0.f, 0.f, 0.f, 0.f};

  const ushort_t* vbase0 = &sV[0][0][0] + (size_t)l16 * TS + vcol;
  const ushort_t* vbase1 = &sV[1][0][0] + (size_t)l16 * TS + vcol;

  for (int i = 0; i < NTt; ++i) {
    const int buf = i & 1;
    if (i) {
      DRAIN_ALL();      // retire DMA(i) (flight = full tile i-1 compute)
      __syncthreads();  // all waves done reading buf^1 (tile i-1's buffer)
      if (i + 1 < NTt) issue_tile(sbeg + (i + 1) * TS, buf ^ 1);
    }
    unsigned msk_nxt = (i + 1 < NTt) ? load_mask(sbeg + (i + 1) * TS) : 0u;

    // ---- QK: S^T = K·Q^T, 4 independent chains of 8 ----
    f32x4 a00 = (f32x4){0.f,0.f,0.f,0.f}, a01 = (f32x4){0.f,0.f,0.f,0.f};
    f32x4 a10 = (f32x4){0.f,0.f,0.f,0.f}, a11 = (f32x4){0.f,0.f,0.f,0.f};
    {
      const ushort_t* kh0 = &sK[buf][l16][quad * 8];
      const ushort_t* kh1 = &sK[buf][16 + l16][quad * 8];
#pragma unroll
      for (int kk = 0; kk < 16; kk += 2) {
        f16x8 k00 = *(const f16x8*)(kh0 + kk * 32);
        f16x8 k10 = *(const f16x8*)(kh1 + kk * 32);
        f16x8 k01 = *(const f16x8*)(kh0 + kk * 32 + 32);
        f16x8 k11 = *(const f16x8*)(kh1 + kk * 32 + 32);
        a00 = __builtin_amdgcn_mfma_f32_16x16x32_f16(k00, qa[kk], a00, 0, 0, 0);
        a10 = __builtin_amdgcn_mfma_f32_16x16x32_f16(k10, qa[kk], a10, 0, 0, 0);
        a01 = __builtin_amdgcn_mfma_f32_16x16x32_f16(k01, qa[kk+1], a01, 0, 0, 0);
        a11 = __builtin_amdgcn_mfma_f32_16x16x32_f16(k11, qa[kk+1], a11, 0, 0, 0);
      }
    }
    f32x4 s0v, s1v;
#pragma unroll
    for (int r = 0; r < 4; ++r) { s0v[r] = a00[r] + a01[r]; s1v[r] = a10[r] + a11[r]; }

    // ---- intra-wave masked softmax; lane: q=l16, s=quad*4+r (+16) ----
    const unsigned mb = msk_cur;
    float se0[4], se1[4];
#pragma unroll
    for (int r = 0; r < 4; ++r) {
      se0[r] = ((mb >> (quad * 4 + r)) & 1u)      ? s0v[r] : -1e30f;
      se1[r] = ((mb >> (16 + quad * 4 + r)) & 1u) ? s1v[r] : -1e30f;
    }
    float rmax = fmaxf(fmaxf(fmaxf(se0[0], se0[1]), fmaxf(se0[2], se0[3])),
                       fmaxf(fmaxf(se1[0], se1[1]), fmaxf(se1[2], se1[3])));
    rmax = fmaxf(rmax, __shfl_xor(rmax, 16));
    rmax = fmaxf(rmax, __shfl_xor(rmax, 32));

    ushort_t pb0[4], pb1[4];
    float rsum = 0.f;
#pragma unroll
    for (int r = 0; r < 4; ++r) {
      float p0 = ((mb >> (quad * 4 + r)) & 1u)      ? __expf(se0[r] - rmax) : 0.f;
      float p1 = ((mb >> (16 + quad * 4 + r)) & 1u) ? __expf(se1[r] - rmax) : 0.f;
      pb0[r] = f2h(p0); pb1[r] = f2h(p1);
      rsum += h2f(pb0[r]) + h2f(pb1[r]);
    }
    {  // two 8B writes into this wave's private sP strip
      uint2 w0, w1;
      w0.x = (unsigned)pb0[0] | ((unsigned)pb0[1] << 16);
      w0.y = (unsigned)pb0[2] | ((unsigned)pb0[3] << 16);
      w1.x = (unsigned)pb1[0] | ((unsigned)pb1[1] << 16);
      w1.y = (unsigned)pb1[2] | ((unsigned)pb1[3] << 16);
      *(uint2*)(&sP[wave][l16][quad * 4]) = w0;
      *(uint2*)(&sP[wave][l16][16 + quad * 4]) = w1;
    }
    rsum += __shfl_xor(rsum, 16);
    rsum += __shfl_xor(rsum, 32);

    // ---- register stats update (q = l16) ----
    float m_new = fmaxf(m_ln, rmax);
    float scl   = __expf(rmax - m_new);   // scales this tile's P
    float al_ln = __expf(m_ln - m_new);   // rescales old l / oacc
    bool  grw   = m_new > m_ln;
    l_ln = al_ln * l_ln + scl * rsum;
    m_ln = m_new;

    // ---- gather P A-frag (intra-wave LDS, wave-synchronous) + scale ----
    f16x8 praw = *(const f16x8*)(&sP[wave][l16][quad * 8]);
    f16x8 pa;
    {
      _Float16 sh16 = (_Float16)scl;
#pragma unroll
      for (int j = 0; j < 8; ++j) pa[j] = praw[j] * sh16;  // v_pk_mul_f16
    }

    if (__any((int)grw)) {  // EXACT skip: all alphas == 1 when no max grew
      float al[4];
#pragma unroll
      for (int r = 0; r < 4; ++r) al[r] = __shfl(al_ln, quad * 4 + r);
#pragma unroll
      for (int nt = 0; nt < 32; ++nt)
#pragma unroll
        for (int r = 0; r < 4; ++r) oacc[nt][r] *= al[r];
    }

    // ---- PV: 32 independent MFMAs, swizzled sV reads ----
    const ushort_t* vb_ = buf ? vbase1 : vbase0;
#pragma unroll
    for (int nt = 0; nt < 32; ++nt) {
      f16x8 vb = *(const f16x8*)(vb_ + nt * 512);
      oacc[nt] = __builtin_amdgcn_mfma_f32_16x16x32_f16(pa, vb, oacc[nt], 0, 0, 0);
    }

    msk_cur = msk_nxt;
  }

  // ---- epilogue: partial results ----
  const size_t rbase = (size_t)(b * SPLIT + sh) * NQz + q0 + wave * 16;
#pragma unroll
  for (int nt = 0; nt < 32; ++nt) {
#pragma unroll
    for (int r = 0; r < 4; ++r) {
      Opart[(rbase + quad * 4 + r) * Dz + nt * 16 + l16] = f2h(oacc[nt][r]);
    }
  }
  if (quad == 0) {
    Mpart[rbase + l16] = m_ln;
    Lpart[rbase + l16] = l_ln;
  }

  // ---- fused split-k combine: last-arriving WG merges (no waiting) ----
  __threadfence();                 // device-scope release of our stores
  __shared__ int sLast;
  __syncthreads();                 // all threads' stores+fences done
  if (tid == 0) sLast = atomicAdd(&Cnt[b * 8 + qt], 1);
  __syncthreads();                 // sLast uniform across WG
  if (sLast == SPLIT - 1) {
    __threadfence();               // acquire side
    __shared__ float sW[SPLIT][QTT];
    __shared__ float sInv[QTT];
    for (int rr = tid; rr < QTT; rr += 512) {
      float mv[SPLIT], lv[SPLIT], mmax = -1e30f;
#pragma unroll
      for (int p = 0; p < SPLIT; ++p) {
        size_t ip = (size_t)(b * SPLIT + p) * NQz + q0 + rr;
        mv[p] = Mpart[ip]; lv[p] = Lpart[ip];
        mmax = fmaxf(mmax, mv[p]);
      }
      float den = 0.f;
#pragma unroll
      for (int p = 0; p < SPLIT; ++p) {
        float w = __expf(mv[p] - mmax);
        sW[p][rr] = w;
        den += w * lv[p];
      }
      sInv[rr] = 1.0f / den;
    }
    __syncthreads();
    const int col = tid & 127;          // 8B column (4 f16), coalesced
    const int rg  = tid >> 7;           // 0..3 row-group
    for (int rr = rg * 32; rr < rg * 32 + 32; ++rr) {
      float inv = sInv[rr];
      float4 acc = {0.f, 0.f, 0.f, 0.f};
#pragma unroll
      for (int p = 0; p < SPLIT; ++p) {
        size_t ip = ((size_t)(b * SPLIT + p) * NQz + q0 + rr) * Dz + col * 4;
        uint2 raw = *(const uint2*)(Opart + ip);
        float w = sW[p][rr];
        acc.x += w * h2f((ushort_t)(raw.x & 0xffff));
        acc.y += w * h2f((ushort_t)(raw.x >> 16));
        acc.z += w * h2f((ushort_t)(raw.y & 0xffff));
        acc.w += w * h2f((ushort_t)(raw.y >> 16));
      }
      acc.x *= inv; acc.y *= inv; acc.z *= inv; acc.w *= inv;
      *(float4*)(Out + ((size_t)b * NQz + q0 + rr) * Dz + col * 4) = acc;
    }
  }
}

extern "C" void kernel_launch(void* const* d_in, const int* in_sizes, int n_in,
                              void* d_out, int out_size, void* d_ws, size_t ws_size,
                              hipStream_t stream) {
  const float* Q = (const float*)d_in[0];
  const float* K = (const float*)d_in[1];
  const float* V = (const float*)d_in[2];
  const int*   M = (const int*)d_in[3];
  float* O = (float*)d_out;

  const size_t NKV   = (size_t)Bz * Sz * Dz;        // f16 elems per tensor
  const size_t maskW = (size_t)Bz * NQz * (Sz / 32);

  // Split-independent layout: Kf | Vt | Mp | Cnt(64) | Opart(fp16) | Mpart | Lpart
  ushort_t* Kf = (ushort_t*)d_ws;
  ushort_t* Vt = Kf + NKV;
  unsigned* Mp = (unsigned*)(Vt + NKV);
  int* Cnt = (int*)(Mp + maskW);
  ushort_t* Opart = (ushort_t*)(Cnt + 64);

  auto need_bytes = [&](int S) -> size_t {
    return NKV * 2 * 2 + maskW * 4 + 256
         + (size_t)Bz * S * NQz * Dz * 2       // Opart fp16
         + (size_t)Bz * S * NQz * 4 * 2;       // Mpart + Lpart
  };

  // 2048 K-convert + 4096 V-transpose + 4096 mask-pack blocks
  prep<<<dim3(10240), dim3(256), 0, stream>>>(K, V, M, Kf, Vt, Mp, Cnt);

  if (ws_size >= need_bytes(4)) {
    constexpr int S = 4;
    float* Mpart = (float*)(Opart + (size_t)Bz * S * NQz * Dz);
    float* Lpart = Mpart + (size_t)Bz * S * NQz;
    attn_flash<S><<<dim3(8 * (NQz / QTT) * S), dim3(512), 0, stream>>>(
        Q, Mp, Kf, Vt, Opart, Mpart, Lpart, Cnt, O);
  } else {
    constexpr int S = 2;
    float* Mpart = (float*)(Opart + (size_t)Bz * S * NQz * Dz);
    float* Lpart = Mpart + (size_t)Bz * S * NQz;
    attn_flash<S><<<dim3(8 * (NQz / QTT) * S), dim3(512), 0, stream>>>(
        Q, Mp, Kf, Vt, Opart, Mpart, Lpart, Cnt, O);
  }
}

// Round 11
// 244.610 us; speedup vs baseline: 1.4493x; 1.4493x over previous
//
#include <hip/hip_runtime.h>

// Masked attention B=8, NQ=1024, S=2048, D=512, fp32 in/out.
// prep: K -> Kf fp16; V -> Vt fp16 [b][d][s]; mask -> bit-packed Mp (2MB).
// attn_flash r19 = r12 core (proven 83.5-84.7us across r4/r7/r9 runs) +
//   s_setprio(1) around QK/PV MFMA clusters (T5; waves drift between
//   barriers -> phase diversity) + unquantized rsum (drops 8 h2f/tile from
//   the serial softmax chain; l tracks pre-quantization sum).
//   r18's fused split-k combine REVERTED: per-WG device-scope threadfence
//   added ~117us of L2-writeback/invalidate stalls (attn 84->201).
// combine: separate kernel (measured ~9us, stream-ordered), SPLIT S-parts.

#define Bz 8
#define NQz 1024
#define Sz 2048
#define Dz 512
#define QTT 128   // q rows per WG (8 waves x 16)
#define TS 32
#define KP 520    // sK row pitch (f16); 1040B rows
#define PP 40     // sP row pitch (f16)

typedef _Float16 f16x8 __attribute__((ext_vector_type(8)));
typedef float f32x4 __attribute__((ext_vector_type(4)));
typedef unsigned short ushort_t;

#define AS1(p) ((const __attribute__((address_space(1))) unsigned int*)(p))
#define AS3(p) ((__attribute__((address_space(3))) unsigned int*)(p))
#define DRAIN_ALL() __builtin_amdgcn_s_waitcnt(0)

__device__ __forceinline__ ushort_t f2h(float x) {
  _Float16 h = (_Float16)x;  // RNE
  return __builtin_bit_cast(ushort_t, h);
}
__device__ __forceinline__ float h2f(ushort_t u) {
  return (float)__builtin_bit_cast(_Float16, u);
}

// ---- prep: K -> fp16 | V -> Vt fp16 transposed | mask -> bitpack ----
__global__ __launch_bounds__(256)
void prep(const float* __restrict__ K, const float* __restrict__ V,
          const int* __restrict__ Mi, ushort_t* __restrict__ Kf,
          ushort_t* __restrict__ Vt, unsigned* __restrict__ Mp) {
  __shared__ ushort_t sT[64][41];
  const int t = threadIdx.x;
  int bx = blockIdx.x;
  if (bx < 2048) {  // K fp32 -> fp16: 16 elems/thread, 4 independent streams
    const size_t base = (size_t)bx * 4096 + t * 4;
#pragma unroll
    for (int i = 0; i < 4; ++i) {
      size_t e = base + i * 1024;
      float4 v = *(const float4*)(K + e);
      uint2 w;
      w.x = (unsigned)f2h(v.x) | ((unsigned)f2h(v.y) << 16);
      w.y = (unsigned)f2h(v.z) | ((unsigned)f2h(v.w) << 16);
      *(uint2*)(Kf + e) = w;
    }
    return;
  }
  bx -= 2048;
  if (bx < 4096) {  // V transpose, 64s x 32d tiles, 128B write segments
    const int b = bx >> 9;
    const int rest = bx & 511;
    const int st = rest >> 4;
    const int dt = rest & 15;
    const int s0 = st * 64, d0 = dt * 32;
    const float* Vb = V + ((size_t)b * Sz + s0) * Dz + d0;
#pragma unroll
    for (int i = 0; i < 2; ++i) {
      int idx = t + 256 * i;
      int s = idx >> 3;
      int dc = (idx & 7) * 4;
      float4 v = *(const float4*)(Vb + (size_t)s * Dz + dc);
      uint2 w;
      w.x = (unsigned)f2h(v.x) | ((unsigned)f2h(v.y) << 16);
      w.y = (unsigned)f2h(v.z) | ((unsigned)f2h(v.w) << 16);
      *(uint2*)(&sT[s][dc]) = w;
    }
    __syncthreads();
    ushort_t* VtB = Vt + ((size_t)b * Dz + d0) * Sz + s0;
    int d = t >> 3, c = t & 7;
    uint4 u;
    ushort_t* tp = (ushort_t*)&u;
#pragma unroll
    for (int j = 0; j < 8; ++j) tp[j] = sT[c * 8 + j][d];
    *(uint4*)(VtB + (size_t)d * Sz + c * 8) = u;
    return;
  }
  bx -= 4096;  // mask bitpack: 4096 ints/block over 4 iterations
  const int lane = t & 63;
#pragma unroll
  for (int i = 0; i < 4; ++i) {
    const size_t base = (size_t)bx * 4096 + i * 1024 + t * 4;
    const int4 mv = *(const int4*)(Mi + base);
    unsigned nib = (mv.x ? 1u : 0u) | (mv.y ? 2u : 0u) |
                   (mv.z ? 4u : 0u) | (mv.w ? 8u : 0u);
    unsigned v = nib << ((lane & 7) * 4);
    v |= __shfl_xor(v, 1);
    v |= __shfl_xor(v, 2);
    v |= __shfl_xor(v, 4);
    if ((lane & 7) == 0) Mp[bx * 128 + i * 32 + (t >> 3)] = v;
  }
}

// ---------------- attention (r12 core + setprio + rsum trim) ----------------
template <int SPLIT>
__global__ __launch_bounds__(512, 2)
void attn_flash(const float* __restrict__ Q, const unsigned* __restrict__ Mp,
                const ushort_t* __restrict__ Kf, const ushort_t* __restrict__ Vt,
                ushort_t* __restrict__ Opart, float* __restrict__ Mpart,
                float* __restrict__ Lpart) {
  __shared__ ushort_t sK[2][TS][KP];    // 66.56 KB
  __shared__ ushort_t sV[2][Dz][TS];    // 65.54 KB (16B-slot XOR-swizzled)
  __shared__ ushort_t sP[8][16][PP];    // 10.24 KB, per-wave private strips

  const int tid  = threadIdx.x;
  const int wave = tid >> 6;
  const int lane = tid & 63;
  const int l16  = lane & 15;
  const int quad = lane >> 4;

  const int bxr = blockIdx.x;
  const int b   = bxr & 7;               // XCD swizzle: b == XCD
  const int rest = bxr >> 3;
  const int qt  = rest / SPLIT;
  const int sh  = rest % SPLIT;
  const int q0  = qt * QTT;
  const int SLEN = Sz / SPLIT;
  const int NTt  = SLEN / TS;
  const int sbeg = sh * SLEN;
  const int qw   = q0 + wave * 16;       // this wave's q base

  const float*    Qb  = Q  + ((size_t)b * NQz + qw) * Dz;
  const ushort_t* KfB = Kf + (size_t)b * Sz * Dz;
  const ushort_t* VtB = Vt + (size_t)b * Dz * Sz;
  const unsigned* MpB = Mp + ((size_t)b * NQz + qw) * (Sz / 32);

  // sV swizzle: physical 16B slot = logical_quad ^ ((d>>1)&3).
  const int vql  = (lane & 3) ^ ((lane >> 3) & 3);   // DMA source slot
  const int vcol = (quad ^ ((l16 >> 1) & 3)) * 8;    // read slot (f16 elems)

  auto issue_tile = [&](int s0n, int bsel) {
#pragma unroll
    for (int j = 0; j < 4; ++j) {  // K: 32 rows, 1 row (1024B) per instr
      int row = wave * 4 + j;
      const ushort_t* gp = KfB + (size_t)(s0n + row) * Dz + lane * 8;
      __builtin_amdgcn_global_load_lds(AS1(gp), AS3(&sK[bsel][row][0]), 16, 0, 0);
    }
#pragma unroll
    for (int j = 0; j < 4; ++j) {  // V: 512 d-rows of 64B, 16 rows per instr
      int dbase = wave * 64 + j * 16;
      int d = dbase + (lane >> 2);
      const ushort_t* gp = VtB + (size_t)d * Sz + s0n + vql * 8;
      __builtin_amdgcn_global_load_lds(AS1(gp), AS3(&sV[bsel][dbase][0]), 16, 0, 0);
    }
  };
  auto load_mask = [&](int s0n) -> unsigned {
    return MpB[(size_t)l16 * (Sz / 32) + (s0n >> 5)];
  };

  // ---- prologue: DMA(0), mask(0), Q frags, DMA(1) ----
  issue_tile(sbeg, 0);
  unsigned msk_cur = load_mask(sbeg);

  f16x8 qa[16];  // Q rows qw+l16, fp16; B-operand of swapped QK
  {
    const float* qrow = Qb + (size_t)l16 * Dz;
#pragma unroll
    for (int kk = 0; kk < 16; ++kk) {
      const float4 a = *(const float4*)(qrow + kk * 32 + quad * 8);
      const float4 c = *(const float4*)(qrow + kk * 32 + quad * 8 + 4);
      f16x8 h;
      h[0] = (_Float16)a.x; h[1] = (_Float16)a.y;
      h[2] = (_Float16)a.z; h[3] = (_Float16)a.w;
      h[4] = (_Float16)c.x; h[5] = (_Float16)c.y;
      h[6] = (_Float16)c.z; h[7] = (_Float16)c.w;
      qa[kk] = h;
    }
  }
  if (NTt > 1) issue_tile(sbeg + TS, 1);
  DRAIN_ALL();       // each wave retires its own DMA portion...
  __syncthreads();   // ...then barrier => whole tile 0 (and 1) visible

  float m_ln = -1e30f, l_ln = 0.0f;  // running stats for q = qw + l16
  f32x4 oacc[32];
#pragma unroll
  for (int nt = 0; nt < 32; ++nt) oacc[nt] = (f32x4){0.f, 0.f, 0.f, 0.f};

  const ushort_t* vbase0 = &sV[0][0][0] + (size_t)l16 * TS + vcol;
  const ushort_t* vbase1 = &sV[1][0][0] + (size_t)l16 * TS + vcol;

  for (int i = 0; i < NTt; ++i) {
    const int buf = i & 1;
    if (i) {
      DRAIN_ALL();      // retire DMA(i) (flight = full tile i-1 compute)
      __syncthreads();  // all waves done reading buf^1 (tile i-1's buffer)
      if (i + 1 < NTt) issue_tile(sbeg + (i + 1) * TS, buf ^ 1);
    }
    unsigned msk_nxt = (i + 1 < NTt) ? load_mask(sbeg + (i + 1) * TS) : 0u;

    // ---- QK: S^T = K·Q^T, 4 independent chains of 8 ----
    f32x4 a00 = (f32x4){0.f,0.f,0.f,0.f}, a01 = (f32x4){0.f,0.f,0.f,0.f};
    f32x4 a10 = (f32x4){0.f,0.f,0.f,0.f}, a11 = (f32x4){0.f,0.f,0.f,0.f};
    {
      const ushort_t* kh0 = &sK[buf][l16][quad * 8];
      const ushort_t* kh1 = &sK[buf][16 + l16][quad * 8];
      __builtin_amdgcn_s_setprio(1);
#pragma unroll
      for (int kk = 0; kk < 16; kk += 2) {
        f16x8 k00 = *(const f16x8*)(kh0 + kk * 32);
        f16x8 k10 = *(const f16x8*)(kh1 + kk * 32);
        f16x8 k01 = *(const f16x8*)(kh0 + kk * 32 + 32);
        f16x8 k11 = *(const f16x8*)(kh1 + kk * 32 + 32);
        a00 = __builtin_amdgcn_mfma_f32_16x16x32_f16(k00, qa[kk], a00, 0, 0, 0);
        a10 = __builtin_amdgcn_mfma_f32_16x16x32_f16(k10, qa[kk], a10, 0, 0, 0);
        a01 = __builtin_amdgcn_mfma_f32_16x16x32_f16(k01, qa[kk+1], a01, 0, 0, 0);
        a11 = __builtin_amdgcn_mfma_f32_16x16x32_f16(k11, qa[kk+1], a11, 0, 0, 0);
      }
      __builtin_amdgcn_s_setprio(0);
    }
    f32x4 s0v, s1v;
#pragma unroll
    for (int r = 0; r < 4; ++r) { s0v[r] = a00[r] + a01[r]; s1v[r] = a10[r] + a11[r]; }

    // ---- intra-wave masked softmax; lane: q=l16, s=quad*4+r (+16) ----
    const unsigned mb = msk_cur;
    float se0[4], se1[4];
#pragma unroll
    for (int r = 0; r < 4; ++r) {
      se0[r] = ((mb >> (quad * 4 + r)) & 1u)      ? s0v[r] : -1e30f;
      se1[r] = ((mb >> (16 + quad * 4 + r)) & 1u) ? s1v[r] : -1e30f;
    }
    float rmax = fmaxf(fmaxf(fmaxf(se0[0], se0[1]), fmaxf(se0[2], se0[3])),
                       fmaxf(fmaxf(se1[0], se1[1]), fmaxf(se1[2], se1[3])));
    rmax = fmaxf(rmax, __shfl_xor(rmax, 16));
    rmax = fmaxf(rmax, __shfl_xor(rmax, 32));

    ushort_t pb0[4], pb1[4];
    float rsum = 0.f;
#pragma unroll
    for (int r = 0; r < 4; ++r) {
      float p0 = ((mb >> (quad * 4 + r)) & 1u)      ? __expf(se0[r] - rmax) : 0.f;
      float p1 = ((mb >> (16 + quad * 4 + r)) & 1u) ? __expf(se1[r] - rmax) : 0.f;
      pb0[r] = f2h(p0); pb1[r] = f2h(p1);
      rsum += p0 + p1;   // unquantized sum (closer to fp32 reference; -8 h2f)
    }
    {  // two 8B writes into this wave's private sP strip
      uint2 w0, w1;
      w0.x = (unsigned)pb0[0] | ((unsigned)pb0[1] << 16);
      w0.y = (unsigned)pb0[2] | ((unsigned)pb0[3] << 16);
      w1.x = (unsigned)pb1[0] | ((unsigned)pb1[1] << 16);
      w1.y = (unsigned)pb1[2] | ((unsigned)pb1[3] << 16);
      *(uint2*)(&sP[wave][l16][quad * 4]) = w0;
      *(uint2*)(&sP[wave][l16][16 + quad * 4]) = w1;
    }
    rsum += __shfl_xor(rsum, 16);
    rsum += __shfl_xor(rsum, 32);

    // ---- register stats update (q = l16) ----
    float m_new = fmaxf(m_ln, rmax);
    float scl   = __expf(rmax - m_new);   // scales this tile's P
    float al_ln = __expf(m_ln - m_new);   // rescales old l / oacc
    bool  grw   = m_new > m_ln;
    l_ln = al_ln * l_ln + scl * rsum;
    m_ln = m_new;

    // ---- gather P A-frag (intra-wave LDS, wave-synchronous) + scale ----
    f16x8 praw = *(const f16x8*)(&sP[wave][l16][quad * 8]);
    f16x8 pa;
    {
      _Float16 sh16 = (_Float16)scl;
#pragma unroll
      for (int j = 0; j < 8; ++j) pa[j] = praw[j] * sh16;  // v_pk_mul_f16
    }

    if (__any((int)grw)) {  // EXACT skip: all alphas == 1 when no max grew
      float al[4];
#pragma unroll
      for (int r = 0; r < 4; ++r) al[r] = __shfl(al_ln, quad * 4 + r);
#pragma unroll
      for (int nt = 0; nt < 32; ++nt)
#pragma unroll
        for (int r = 0; r < 4; ++r) oacc[nt][r] *= al[r];
    }

    // ---- PV: 32 independent MFMAs, swizzled sV reads ----
    const ushort_t* vb_ = buf ? vbase1 : vbase0;
    __builtin_amdgcn_s_setprio(1);
#pragma unroll
    for (int nt = 0; nt < 32; ++nt) {
      f16x8 vb = *(const f16x8*)(vb_ + nt * 512);
      oacc[nt] = __builtin_amdgcn_mfma_f32_16x16x32_f16(pa, vb, oacc[nt], 0, 0, 0);
    }
    __builtin_amdgcn_s_setprio(0);

    msk_cur = msk_nxt;
  }

  // ---- epilogue: no barrier needed (all state register/private) ----
  const size_t rbase = (size_t)(b * SPLIT + sh) * NQz + q0 + wave * 16;
#pragma unroll
  for (int nt = 0; nt < 32; ++nt) {
#pragma unroll
    for (int r = 0; r < 4; ++r) {
      Opart[(rbase + quad * 4 + r) * Dz + nt * 16 + l16] = f2h(oacc[nt][r]);
    }
  }
  if (quad == 0) {
    Mpart[rbase + l16] = m_ln;
    Lpart[rbase + l16] = l_ln;
  }
}

// ---------------- combine the SPLIT S-parts (fp16 Opart) ----------------
template <int SPLIT>
__global__ __launch_bounds__(256)
void combine(const ushort_t* __restrict__ Opart, const float* __restrict__ Mpart,
             const float* __restrict__ Lpart, float* __restrict__ Out) {
  int gid = blockIdx.x * 256 + threadIdx.x;
  int row = gid >> 7;
  int b   = row >> 10;
  int q   = row & 1023;
  int c   = (gid & 127) * 4;
  float mv[SPLIT], lv[SPLIT];
  float m = -1e30f;
#pragma unroll
  for (int p = 0; p < SPLIT; ++p) {
    size_t ip = (size_t)(b * SPLIT + p) * NQz + q;
    mv[p] = Mpart[ip];
    lv[p] = Lpart[ip];
    m = fmaxf(m, mv[p]);
  }
  float w[SPLIT], denom = 0.f;
#pragma unroll
  for (int p = 0; p < SPLIT; ++p) {
    w[p] = __expf(mv[p] - m);
    denom += w[p] * lv[p];
  }
  float inv = 1.0f / denom;
  float4 o = {0.f, 0.f, 0.f, 0.f};
#pragma unroll
  for (int p = 0; p < SPLIT; ++p) {
    size_t ip = (size_t)(b * SPLIT + p) * NQz + q;
    const ushort_t* op = Opart + ip * Dz + c;
    uint2 raw = *(const uint2*)op;
    o.x += w[p] * h2f((ushort_t)(raw.x & 0xffff));
    o.y += w[p] * h2f((ushort_t)(raw.x >> 16));
    o.z += w[p] * h2f((ushort_t)(raw.y & 0xffff));
    o.w += w[p] * h2f((ushort_t)(raw.y >> 16));
  }
  o.x *= inv; o.y *= inv; o.z *= inv; o.w *= inv;
  *(float4*)(Out + ((size_t)b * NQz + q) * Dz + c) = o;
}

extern "C" void kernel_launch(void* const* d_in, const int* in_sizes, int n_in,
                              void* d_out, int out_size, void* d_ws, size_t ws_size,
                              hipStream_t stream) {
  const float* Q = (const float*)d_in[0];
  const float* K = (const float*)d_in[1];
  const float* V = (const float*)d_in[2];
  const int*   M = (const int*)d_in[3];
  float* O = (float*)d_out;

  const size_t NKV   = (size_t)Bz * Sz * Dz;        // f16 elems per tensor
  const size_t maskW = (size_t)Bz * NQz * (Sz / 32);

  // Split-independent layout: Kf | Vt | Mp | Opart(fp16) | Mpart | Lpart
  ushort_t* Kf = (ushort_t*)d_ws;
  ushort_t* Vt = Kf + NKV;
  unsigned* Mp = (unsigned*)(Vt + NKV);
  ushort_t* Opart = (ushort_t*)(Mp + maskW);

  auto need_bytes = [&](int S) -> size_t {
    return NKV * 2 * 2 + maskW * 4
         + (size_t)Bz * S * NQz * Dz * 2       // Opart fp16
         + (size_t)Bz * S * NQz * 4 * 2;       // Mpart + Lpart
  };

  // 2048 K-convert + 4096 V-transpose + 4096 mask-pack blocks
  prep<<<dim3(10240), dim3(256), 0, stream>>>(K, V, M, Kf, Vt, Mp);

  if (ws_size >= need_bytes(4)) {
    constexpr int S = 4;
    float* Mpart = (float*)(Opart + (size_t)Bz * S * NQz * Dz);
    float* Lpart = Mpart + (size_t)Bz * S * NQz;
    attn_flash<S><<<dim3(8 * (NQz / QTT) * S), dim3(512), 0, stream>>>(
        Q, Mp, Kf, Vt, Opart, Mpart, Lpart);
    combine<S><<<dim3(4096), dim3(256), 0, stream>>>(Opart, Mpart, Lpart, O);
  } else {
    constexpr int S = 2;
    float* Mpart = (float*)(Opart + (size_t)Bz * S * NQz * Dz);
    float* Lpart = Mpart + (size_t)Bz * S * NQz;
    attn_flash<S><<<dim3(8 * (NQz / QTT) * S), dim3(512), 0, stream>>>(
        Q, Mp, Kf, Vt, Opart, Mpart, Lpart);
    combine<S><<<dim3(4096), dim3(256), 0, stream>>>(Opart, Mpart, Lpart, O);
  }
}